// Round 9
// baseline (1847265.430 us; speedup 1.0000x reference)
//
#include <hip/hip_runtime.h>
#include <stdint.h>

typedef _Float16 f16;
typedef f16 f16x2 __attribute__((ext_vector_type(2)));

#define T_LEN 32768
#define HID   512
#define IN_D  1024
#define OUT_D 128
#define NT    1024
// Thread t: rows [(t>>4)*8, +8), k-slice [(t&15)*32, +32).
// Per-thread W: 32 uint4, j = c*8 + rl  (c = k-quarter 0..3, rl = row-local 0..7):
//   j  0..19 -> VGPR wreg[80]           (c0,c1 all rows; c2 rows 0..3)
//   j 20..26 -> LDS wlds4[(j-20)*NT+t]  (c2 rows 4..7; c3 rows 0..2)  114KB
//   j 27..31 -> L2 stream               (c3 rows 3..7)  80KB/matvec, stays L2-hot

__device__ __forceinline__ float dot2f(uint32_t w, uint32_t v, float acc) {
    return __builtin_amdgcn_fdot2(__builtin_bit_cast(f16x2, w),
                                  __builtin_bit_cast(f16x2, v), acc, false);
}
__device__ __forceinline__ float fast_tanh(float z) {
    float e = __expf(2.f * z);
    return 1.f - 2.f * __builtin_amdgcn_rcpf(e + 1.f);
}

// ---------------------------------------------------------------------------
// K0: pack W (fp32) -> f16x2, layout dst4[j*NT + t]; element (j,mm):
// c=j>>3, rl=j&7, row=(t>>4)*8+rl, k0=(t&15)*32 + c*8 + mm*2.
// ---------------------------------------------------------------------------
__global__ __launch_bounds__(NT) void k_prep(const float* __restrict__ W_ode,
                                             const float* __restrict__ W_h,
                                             uint32_t* __restrict__ ode_prep,
                                             uint32_t* __restrict__ wh_prep) {
    const int t = threadIdx.x;
    const float* W = blockIdx.x ? W_h : W_ode;
    uint4* dst = (uint4*)(blockIdx.x ? wh_prep : ode_prep);
    const int rg = t >> 4, kg = t & 15;
    for (int j = 0; j < 32; ++j) {
        const int c = j >> 3, rl = j & 7;
        const int row = rg * 8 + rl;
        uint32_t cc[4];
#pragma unroll
        for (int mm = 0; mm < 4; ++mm) {
            const int k0 = kg * 32 + c * 8 + mm * 2;
            f16x2 pk;
            pk[0] = (f16)W[row * HID + k0];
            pk[1] = (f16)W[row * HID + k0 + 1];
            cc[mm] = __builtin_bit_cast(uint32_t, pk);
        }
        dst[j * NT + t] = uint4{cc[0], cc[1], cc[2], cc[3]};
    }
}

// ---------------------------------------------------------------------------
// K1: pre[i][j] = W_in @ x_i + b_in + b_h   (fp32 tiled GEMM) — unchanged.
// ---------------------------------------------------------------------------
__global__ __launch_bounds__(512) void k_pre(const float* __restrict__ x,
                                             const float* __restrict__ W_in,
                                             const float* __restrict__ b_in,
                                             const float* __restrict__ b_h,
                                             float* __restrict__ pre32,
                                             uint16_t* __restrict__ pre16,
                                             int preF32) {
    __shared__ float xs[64][34];
    __shared__ float wsh[256][34];
    const int t  = threadIdx.x;
    const int i0 = (blockIdx.x >> 1) * 64;
    const int j0 = (blockIdx.x & 1) * 256;
    const int ti = t >> 5, tj = t & 31;

    float acc[4][8];
#pragma unroll
    for (int a = 0; a < 4; ++a)
#pragma unroll
        for (int b = 0; b < 8; ++b) acc[a][b] = 0.f;

    for (int kb = 0; kb < 32; ++kb) {
        __syncthreads();
        {
            int r = t >> 3, c = (t & 7) * 4;
            float4 v = *(const float4*)&x[(size_t)(i0 + r) * IN_D + kb * 32 + c];
            xs[r][c] = v.x; xs[r][c + 1] = v.y; xs[r][c + 2] = v.z; xs[r][c + 3] = v.w;
        }
        {
            int jr = t >> 1, c0 = (t & 1) * 16;
#pragma unroll
            for (int qd = 0; qd < 4; ++qd) {
                float4 v = *(const float4*)&W_in[(size_t)(j0 + jr) * IN_D + kb * 32 + c0 + qd * 4];
                wsh[jr][c0 + qd * 4]     = v.x; wsh[jr][c0 + qd * 4 + 1] = v.y;
                wsh[jr][c0 + qd * 4 + 2] = v.z; wsh[jr][c0 + qd * 4 + 3] = v.w;
            }
        }
        __syncthreads();
#pragma unroll 4
        for (int k = 0; k < 32; ++k) {
            float xv[4], wv[8];
#pragma unroll
            for (int ii = 0; ii < 4; ++ii) xv[ii] = xs[ti * 4 + ii][k];
#pragma unroll
            for (int jj = 0; jj < 8; ++jj) wv[jj] = wsh[tj + 32 * jj][k];
#pragma unroll
            for (int ii = 0; ii < 4; ++ii)
#pragma unroll
                for (int jj = 0; jj < 8; ++jj)
                    acc[ii][jj] = fmaf(xv[ii], wv[jj], acc[ii][jj]);
        }
    }
#pragma unroll
    for (int ii = 0; ii < 4; ++ii)
#pragma unroll
        for (int jj = 0; jj < 8; ++jj) {
            int ig = i0 + ti * 4 + ii, jg = j0 + tj + 32 * jj;
            float r = acc[ii][jj] + b_in[jg] + b_h[jg];
            if (preF32) pre32[(size_t)ig * HID + jg] = r;
            else        pre16[(size_t)ig * HID + jg] = __builtin_bit_cast(uint16_t, (f16)r);
        }
}

// ---------------------------------------------------------------------------
// K2: sequential scan, 1 CU, 1024 threads (16 waves, 4/SIMD, RA-native 128
// VGPR). 16 k-groups halve the vv LDS reads (4 b128 per matvec). vbuf chunks
// padded to 72B -> 16 broadcast addrs hit distinct bank-quads (<=2-way, free).
// Design invariant: <=120 live VGPRs (no prefetch blocks; read-at-use + queue).
// ---------------------------------------------------------------------------
#define WR(j) (uint4{wreg[4*(j)], wreg[4*(j)+1], wreg[4*(j)+2], wreg[4*(j)+3]})

__global__ __launch_bounds__(NT) void k_scan(
    const uint32_t* __restrict__ ode_prep, const uint32_t* __restrict__ wh_prep,
    const float* __restrict__ pre32, const uint16_t* __restrict__ pre16, int preF32,
    const float* __restrict__ tarr, const float* __restrict__ b_ode,
    const float* __restrict__ W_dec, const float* __restrict__ b_dec,
    float* __restrict__ out)
{
    __shared__ uint4 wlds4[7 * NT];                   // 114688 B, lane-contiguous
    __shared__ __align__(16) uint16_t vbuf[2][576];   // 16 chunks x 36 f16 (72B)
    __shared__ float hbuf[HID];

    const int t   = threadIdx.x;
    const int kg  = t & 15;
    const int rg  = t >> 4;
    const int row = rg * 8 + (kg & 7);
    const uint4* ode4 = (const uint4*)ode_prep;
    const uint4* wh4  = (const uint4*)wh_prep;

    uint32_t wreg[80];
#pragma unroll
    for (int j = 0; j < 20; ++j) {
        uint4 w = ode4[j * NT + t];
        wreg[4 * j] = w.x; wreg[4 * j + 1] = w.y;
        wreg[4 * j + 2] = w.z; wreg[4 * j + 3] = w.w;
    }
#pragma unroll
    for (int c = 0; c < 7; ++c)
        wlds4[c * NT + t] = ode4[(20 + c) * NT + t];

    const float bo = b_ode[row];
    __syncthreads();

    int cur = 1;
    auto push1 = [&](float val) {          // owner lanes (kg<8) publish v[row]
        int nxt = cur ^ 1;
        if (kg < 8)
            vbuf[nxt][(row >> 5) * 36 + (row & 31)] =
                __builtin_bit_cast(uint16_t, (f16)val);
        __syncthreads();
        cur = nxt;
    };

    auto dots4 = [&](uint4 w, uint4 vv, float& a) {
        a = dot2f(w.x, vv.x, a); a = dot2f(w.y, vv.y, a);
        a = dot2f(w.z, vv.z, a); a = dot2f(w.w, vv.w, a);
    };

    // payload-halving butterfly over 16 kg lanes (masks 1,2,4) + allreduce(8):
    // lane ends with full z of row rg*8 + (kg&7).
    auto reduce8 = [&](float acc[8]) -> float {
        const bool o1 = kg & 1, o2 = (kg >> 1) & 1, o4 = (kg >> 2) & 1;
        float b[4];
#pragma unroll
        for (int j = 0; j < 4; ++j) {
            float got = __shfl_xor(o1 ? acc[2 * j] : acc[2 * j + 1], 1);
            b[j] = (o1 ? acc[2 * j + 1] : acc[2 * j]) + got;
        }
        float c[2];
#pragma unroll
        for (int i2 = 0; i2 < 2; ++i2) {
            float got = __shfl_xor(o2 ? b[2 * i2] : b[2 * i2 + 1], 2);
            c[i2] = (o2 ? b[2 * i2 + 1] : b[2 * i2]) + got;
        }
        float got = __shfl_xor(o4 ? c[0] : c[1], 4);
        float d = (o4 ? c[1] : c[0]) + got;
        d += __shfl_xor(d, 8);
        return d;
    };

    // z = (W_ode v)[row]
    auto mv_ode = [&]() -> float {
        float acc[8] = {0.f, 0.f, 0.f, 0.f, 0.f, 0.f, 0.f, 0.f};
        const char* vb = (const char*)&vbuf[cur][0] + kg * 72;
        uint4 s0, s1, s2, s3, s4;
        // c=0: pure wreg
        uint4 vv = *(const uint4*)(vb);
#pragma unroll
        for (int rl = 0; rl < 8; ++rl) dots4(WR(rl), vv, acc[rl]);
        s0 = ode4[27 * NT + t]; s1 = ode4[28 * NT + t]; s2 = ode4[29 * NT + t];
        // c=1: pure wreg
        vv = *(const uint4*)(vb + 16);
#pragma unroll
        for (int rl = 0; rl < 8; ++rl) dots4(WR(8 + rl), vv, acc[rl]);
        s3 = ode4[30 * NT + t]; s4 = ode4[31 * NT + t];
        // c=2: wreg rows 0..3, LDS rows 4..7 (read-at-use; queue hides)
        vv = *(const uint4*)(vb + 32);
        dots4(WR(16), vv, acc[0]); dots4(WR(17), vv, acc[1]);
        dots4(WR(18), vv, acc[2]); dots4(WR(19), vv, acc[3]);
        dots4(wlds4[0 * NT + t], vv, acc[4]);
        dots4(wlds4[1 * NT + t], vv, acc[5]);
        dots4(wlds4[2 * NT + t], vv, acc[6]);
        dots4(wlds4[3 * NT + t], vv, acc[7]);
        // c=3: LDS rows 0..2, stream rows 3..7
        vv = *(const uint4*)(vb + 48);
        dots4(wlds4[4 * NT + t], vv, acc[0]);
        dots4(wlds4[5 * NT + t], vv, acc[1]);
        dots4(wlds4[6 * NT + t], vv, acc[2]);
        dots4(s0, vv, acc[3]); dots4(s1, vv, acc[4]);
        dots4(s2, vv, acc[5]); dots4(s3, vv, acc[6]);
        dots4(s4, vv, acc[7]);
        return reduce8(acc);
    };

    // z = (W_h v)[row]; 512KB streamed from L2, 4-deep named ring
    auto mv_wh = [&]() -> float {
        float acc[8] = {0.f, 0.f, 0.f, 0.f, 0.f, 0.f, 0.f, 0.f};
        const char* vb = (const char*)&vbuf[cur][0] + kg * 72;
        uint4 r0 = wh4[0 * NT + t], r1 = wh4[1 * NT + t];
        uint4 r2 = wh4[2 * NT + t], r3 = wh4[3 * NT + t];
        uint4 vv;
#pragma unroll
        for (int j = 0; j < 32; ++j) {
            const int c = j >> 3, rl = j & 7, sl = j & 3;
            if (rl == 0) vv = *(const uint4*)(vb + c * 16);
            const uint4 w = (sl == 0) ? r0 : (sl == 1) ? r1 : (sl == 2) ? r2 : r3;
            if (j + 4 < 32) {
                const uint4 nw = wh4[(j + 4) * NT + t];
                if (sl == 0) r0 = nw; else if (sl == 1) r1 = nw;
                else if (sl == 2) r2 = nw; else r3 = nw;
            }
            dots4(w, vv, acc[rl]);
        }
        return reduce8(acc);
    };

    // h0 = tanh(pre[0][row])
    float h;
    {
        float p0 = preF32 ? pre32[row] : (float)__builtin_bit_cast(f16, pre16[row]);
        h = fast_tanh(p0);
    }
    push1(h);
    float tprev = tarr[0];

#pragma unroll 1
    for (int i = 1; i < T_LEN; ++i) {
        float tc  = tarr[i];
        float dtt = tc - tprev; tprev = tc;
        float dt  = 0.25f * dtt;            // N_SUB = 4
        float hdt = 0.5f * dt;
        float sixth = dt * (1.f / 6.f);
        float pv = preF32 ? pre32[(size_t)i * HID + row]
                          : (float)__builtin_bit_cast(f16, pre16[(size_t)i * HID + row]);
#pragma unroll 1
        for (int sub = 0; sub < 4; ++sub) {
            float ks = 0.f;
#pragma unroll 1
            for (int s = 0; s < 4; ++s) {
                float z = mv_ode();
                float k = fast_tanh(z + bo);
                float wk = (s == 1 || s == 2) ? 2.f : 1.f;
                ks = fmaf(wk, k, ks);
                float n;
                if (s == 3) { h = fmaf(sixth, ks, h); n = h; }
                else        { float a = (s == 2) ? dt : hdt; n = fmaf(a, k, h); }
                push1(n);
            }
        }
        float zh = mv_wh();
        h = fast_tanh(pv + zh);
        push1(h);
    }

    // decode: out = W_dec @ h + b_dec
    if (kg < 8) hbuf[row] = h;
    __syncthreads();
    if (t < OUT_D) {
        float a = b_dec[t];
#pragma unroll 4
        for (int r4 = 0; r4 < 128; ++r4) {
            float4 w = *(const float4*)&W_dec[t * HID + r4 * 4];
            a = fmaf(w.x, hbuf[r4 * 4],     a);
            a = fmaf(w.y, hbuf[r4 * 4 + 1], a);
            a = fmaf(w.z, hbuf[r4 * 4 + 2], a);
            a = fmaf(w.w, hbuf[r4 * 4 + 3], a);
        }
        out[t] = a;
    }
}

// ---------------------------------------------------------------------------
extern "C" void kernel_launch(void* const* d_in, const int* in_sizes, int n_in,
                              void* d_out, int out_size, void* d_ws, size_t ws_size,
                              hipStream_t stream) {
    const float* tarr  = (const float*)d_in[0];
    const float* x     = (const float*)d_in[1];
    const float* W_in  = (const float*)d_in[2];
    const float* b_in  = (const float*)d_in[3];
    const float* W_h   = (const float*)d_in[4];
    const float* b_h   = (const float*)d_in[5];
    const float* W_ode = (const float*)d_in[6];
    const float* b_ode = (const float*)d_in[7];
    const float* W_dec = (const float*)d_in[8];
    const float* b_dec = (const float*)d_in[9];
    float* out = (float*)d_out;

    uint8_t*  ws       = (uint8_t*)d_ws;
    uint32_t* ode_prep = (uint32_t*)(ws);                  // 512 KB
    uint32_t* wh_prep  = (uint32_t*)(ws + (512u << 10));   // 512 KB
    void*     pre      = (void*)(ws + (1u << 20));         // 64 MB f32 or 32 MB f16

    size_t need32 = (1u << 20) + (size_t)T_LEN * HID * 4 + 4096;
    int preF32 = (ws_size >= need32) ? 1 : 0;

    hipLaunchKernelGGL(k_prep, dim3(2), dim3(NT), 0, stream, W_ode, W_h, ode_prep, wh_prep);
    hipLaunchKernelGGL(k_pre,  dim3(1024), dim3(512), 0, stream, x, W_in, b_in, b_h,
                       (float*)pre, (uint16_t*)pre, preF32);
    hipLaunchKernelGGL(k_scan, dim3(1), dim3(NT), 0, stream, ode_prep, wh_prep,
                       (const float*)pre, (const uint16_t*)pre, preF32,
                       tarr, b_ode, W_dec, b_dec, out);
}

// Round 10
// 594470.947 us; speedup vs baseline: 3.1074x; 3.1074x over previous
//
#include <hip/hip_runtime.h>
#include <stdint.h>

typedef _Float16 f16;
typedef f16 f16x2 __attribute__((ext_vector_type(2)));

#define T_LEN 32768
#define HID   512
#define IN_D  1024
#define OUT_D 128
#define NT    512
#define NBLK  4
#define RPB   128        // rows per block
#define SLICE_DW 32768   // 128KB W slice per block, in dwords

__device__ __forceinline__ float dot2f(uint32_t w, uint32_t v, float acc) {
    return __builtin_amdgcn_fdot2(__builtin_bit_cast(f16x2, w),
                                  __builtin_bit_cast(f16x2, v), acc, false);
}
__device__ __forceinline__ float fast_tanh(float z) {
    float e = __expf(2.f * z);
    return 1.f - 2.f * __builtin_amdgcn_rcpf(e + 1.f);
}

// ---------------------------------------------------------------------------
// K0: pack W (fp32 -> f16x2) into 4 row-slices. Slice c: rows [c*128,+128).
// dst4[j*NT + t], j in [0,16): rl=j&1, c8=j>>1; element (j,mm):
//   row = c*128 + 2*(t>>3) + rl,  k0 = (t&7)*64 + c8*8 + mm*2.
// grid 8: bid<4 -> W_ode slice bid; bid>=4 -> W_h slice bid-4.   (= R7, proven)
// ---------------------------------------------------------------------------
__global__ __launch_bounds__(NT) void k_prep(const float* __restrict__ W_ode,
                                             const float* __restrict__ W_h,
                                             uint32_t* __restrict__ ode_prep,
                                             uint32_t* __restrict__ wh_prep) {
    const int bid = blockIdx.x;
    const int c = bid & 3;
    const float* W = (bid >> 2) ? W_h : W_ode;
    uint4* dst = (uint4*)(((bid >> 2) ? wh_prep : ode_prep) + (size_t)c * SLICE_DW);
    const int t = threadIdx.x, rg = t >> 3, kg = t & 7;
    for (int j = 0; j < 16; ++j) {
        const int rl = j & 1, c8 = j >> 1;
        const int row = c * RPB + 2 * rg + rl;
        uint32_t cc[4];
#pragma unroll
        for (int mm = 0; mm < 4; ++mm) {
            const int k0 = kg * 64 + c8 * 8 + mm * 2;
            f16x2 pk;
            pk[0] = (f16)W[row * HID + k0];
            pk[1] = (f16)W[row * HID + k0 + 1];
            cc[mm] = __builtin_bit_cast(uint32_t, pk);
        }
        dst[j * NT + t] = uint4{cc[0], cc[1], cc[2], cc[3]};
    }
}

// ---------------------------------------------------------------------------
// K1: pre[i][j] = W_in @ x_i + b_in + b_h   (fp32 tiled GEMM) — unchanged.
// ---------------------------------------------------------------------------
__global__ __launch_bounds__(512) void k_pre(const float* __restrict__ x,
                                             const float* __restrict__ W_in,
                                             const float* __restrict__ b_in,
                                             const float* __restrict__ b_h,
                                             float* __restrict__ pre32,
                                             uint16_t* __restrict__ pre16,
                                             int preF32) {
    __shared__ float xs[64][34];
    __shared__ float wsh[256][34];
    const int t  = threadIdx.x;
    const int i0 = (blockIdx.x >> 1) * 64;
    const int j0 = (blockIdx.x & 1) * 256;
    const int ti = t >> 5, tj = t & 31;

    float acc[4][8];
#pragma unroll
    for (int a = 0; a < 4; ++a)
#pragma unroll
        for (int b = 0; b < 8; ++b) acc[a][b] = 0.f;

    for (int kb = 0; kb < 32; ++kb) {
        __syncthreads();
        {
            int r = t >> 3, cc = (t & 7) * 4;
            float4 v = *(const float4*)&x[(size_t)(i0 + r) * IN_D + kb * 32 + cc];
            xs[r][cc] = v.x; xs[r][cc + 1] = v.y; xs[r][cc + 2] = v.z; xs[r][cc + 3] = v.w;
        }
        {
            int jr = t >> 1, c0 = (t & 1) * 16;
#pragma unroll
            for (int qd = 0; qd < 4; ++qd) {
                float4 v = *(const float4*)&W_in[(size_t)(j0 + jr) * IN_D + kb * 32 + c0 + qd * 4];
                wsh[jr][c0 + qd * 4]     = v.x; wsh[jr][c0 + qd * 4 + 1] = v.y;
                wsh[jr][c0 + qd * 4 + 2] = v.z; wsh[jr][c0 + qd * 4 + 3] = v.w;
            }
        }
        __syncthreads();
#pragma unroll 4
        for (int k = 0; k < 32; ++k) {
            float xv[4], wv[8];
#pragma unroll
            for (int ii = 0; ii < 4; ++ii) xv[ii] = xs[ti * 4 + ii][k];
#pragma unroll
            for (int jj = 0; jj < 8; ++jj) wv[jj] = wsh[tj + 32 * jj][k];
#pragma unroll
            for (int ii = 0; ii < 4; ++ii)
#pragma unroll
                for (int jj = 0; jj < 8; ++jj)
                    acc[ii][jj] = fmaf(xv[ii], wv[jj], acc[ii][jj]);
        }
    }
#pragma unroll
    for (int ii = 0; ii < 4; ++ii)
#pragma unroll
        for (int jj = 0; jj < 8; ++jj) {
            int ig = i0 + ti * 4 + ii, jg = j0 + tj + 32 * jj;
            float r = acc[ii][jj] + b_in[jg] + b_h[jg];
            if (preF32) pre32[(size_t)ig * HID + jg] = r;
            else        pre16[(size_t)ig * HID + jg] = __builtin_bit_cast(uint16_t, (f16)r);
        }
}

// ---------------------------------------------------------------------------
// K2: sequential scan on 4 CUs (grid=4). Block c owns rows [c*128,+128):
// W_ode slice fully in VGPRs (64 dw/thread), W_h slice fully in LDS (128KB).
// Exchange: tagged-payload dwords ((m&0xffff)<<16 | f16) via relaxed agent
// atomics — no flags, no fences. 3 fetch waves each do ONE coalesced 128-dword
// tagged load + __all tag check, retry. One __syncthreads per matvec.
// ---------------------------------------------------------------------------
__global__ __launch_bounds__(NT) void k_scan(
    const uint32_t* __restrict__ ode_prep, const uint32_t* __restrict__ wh_prep,
    const float* __restrict__ pre32, const uint16_t* __restrict__ pre16, int preF32,
    const float* __restrict__ tarr, const float* __restrict__ b_ode,
    const float* __restrict__ W_dec, const float* __restrict__ b_dec,
    uint32_t* vx,
    float* __restrict__ out)
{
    __shared__ uint4 whlds[16 * NT];                  // 128KB: W_h slice
    __shared__ __align__(16) uint16_t vbuf[2][576];   // f16 v, 8 chunks x 144B

    const int c    = blockIdx.x;
    const int t    = threadIdx.x;
    const int rg   = t >> 3, kg = t & 7;
    const int lane = t & 63;
    const int wv   = t >> 6;                          // wave id 0..7
    const int rloc = 2 * rg + (kg & 1);
    const int row_glob = c * RPB + rloc;
    const uint4* o4 = (const uint4*)(ode_prep + (size_t)c * SLICE_DW);
    const uint4* h4 = (const uint4*)(wh_prep  + (size_t)c * SLICE_DW);

    uint32_t wreg[64];
#pragma unroll
    for (int j = 0; j < 16; ++j) {
        uint4 w = o4[j * NT + t];
        wreg[4 * j] = w.x; wreg[4 * j + 1] = w.y;
        wreg[4 * j + 2] = w.z; wreg[4 * j + 3] = w.w;
    }
#pragma unroll
    for (int j = 0; j < 16; ++j)
        whlds[j * NT + t] = h4[j * NT + t];

    const float bo = b_ode[row_glob];

    int cur = 1;
    uint32_t m = 0;

    auto reduceZ = [&](float a0, float a1) -> float {
        float mine = (kg & 1) ? a1 : a0;
        float oth  = (kg & 1) ? a0 : a1;
        float b = mine + __shfl_xor(oth, 1);
        b += __shfl_xor(b, 2);
        b += __shfl_xor(b, 4);
        return b;                                // z for row rloc, all lanes
    };

    auto mv_ode = [&]() -> float {
        float a0 = 0.f, a1 = 0.f;
        const char* vb = (const char*)&vbuf[cur][0] + kg * 144;
#pragma unroll
        for (int c8 = 0; c8 < 8; ++c8) {
            const uint4 vv = *(const uint4*)(vb + c8 * 16);
            const int j0 = (c8 * 2) * 4, j1 = (c8 * 2 + 1) * 4;
            a0 = dot2f(wreg[j0],     vv.x, a0);
            a0 = dot2f(wreg[j0 + 1], vv.y, a0);
            a0 = dot2f(wreg[j0 + 2], vv.z, a0);
            a0 = dot2f(wreg[j0 + 3], vv.w, a0);
            a1 = dot2f(wreg[j1],     vv.x, a1);
            a1 = dot2f(wreg[j1 + 1], vv.y, a1);
            a1 = dot2f(wreg[j1 + 2], vv.z, a1);
            a1 = dot2f(wreg[j1 + 3], vv.w, a1);
        }
        return reduceZ(a0, a1);
    };

    auto mv_wh = [&]() -> float {
        float a0 = 0.f, a1 = 0.f;
        const char* vb = (const char*)&vbuf[cur][0] + kg * 144;
#pragma unroll
        for (int c8 = 0; c8 < 8; ++c8) {
            const uint4 vv = *(const uint4*)(vb + c8 * 16);
            const uint4 w0 = whlds[(c8 * 2) * NT + t];
            const uint4 w1 = whlds[(c8 * 2 + 1) * NT + t];
            a0 = dot2f(w0.x, vv.x, a0); a0 = dot2f(w0.y, vv.y, a0);
            a0 = dot2f(w0.z, vv.z, a0); a0 = dot2f(w0.w, vv.w, a0);
            a1 = dot2f(w1.x, vv.x, a1); a1 = dot2f(w1.y, vv.y, a1);
            a1 = dot2f(w1.z, vv.z, a1); a1 = dot2f(w1.w, vv.w, a1);
        }
        return reduceZ(a0, a1);
    };

    // publish own v-slice (tagged dwords) + fetch 3 remote slices; 1 barrier.
    auto pushx = [&](float n) {
        ++m;
        const uint32_t mt = m & 0xffffu;
        const int nxt = cur ^ 1;
        uint32_t* slot = vx + (m & 1) * 512;
        const uint16_t nb = __builtin_bit_cast(uint16_t, (f16)n);
        if (kg < 2) {                                   // owner lanes (kg==rloc&1)
            vbuf[nxt][(row_glob >> 6) * 72 + (row_glob & 63)] = nb;
            __hip_atomic_store(&slot[c * RPB + rloc], (mt << 16) | (uint32_t)nb,
                               __ATOMIC_RELAXED, __HIP_MEMORY_SCOPE_AGENT);
        }
        if (wv >= 1 && wv <= 3) {                       // fetch waves
            const int fb = (c + wv) & 3;                // remote block
            uint32_t* p0 = &slot[fb * RPB + lane];
            uint32_t d0, d1;
            for (;;) {
                d0 = __hip_atomic_load(p0,      __ATOMIC_RELAXED, __HIP_MEMORY_SCOPE_AGENT);
                d1 = __hip_atomic_load(p0 + 64, __ATOMIC_RELAXED, __HIP_MEMORY_SCOPE_AGENT);
                if (__all((d0 >> 16) == mt && (d1 >> 16) == mt)) break;
            }
            vbuf[nxt][(2 * fb) * 72 + lane]     = (uint16_t)d0;   // row fb*128+lane
            vbuf[nxt][(2 * fb + 1) * 72 + lane] = (uint16_t)d1;   // row fb*128+64+lane
        }
        __syncthreads();
        cur = nxt;
    };

    // h0 = tanh(pre[0][row]); exchange as m=1
    float h;
    {
        float p0 = preF32 ? pre32[row_glob] : (float)__builtin_bit_cast(f16, pre16[row_glob]);
        h = fast_tanh(p0);
    }
    pushx(h);
    float tprev = tarr[0];

#pragma unroll 1
    for (int i = 1; i < T_LEN; ++i) {
        float tc  = tarr[i];
        float dtt = tc - tprev; tprev = tc;
        float dt  = 0.25f * dtt;            // N_SUB = 4
        float hdt = 0.5f * dt;
        float sixth = dt * (1.f / 6.f);
        float pv = preF32 ? pre32[(size_t)i * HID + row_glob]
                          : (float)__builtin_bit_cast(f16, pre16[(size_t)i * HID + row_glob]);
#pragma unroll 1
        for (int sub = 0; sub < 4; ++sub) {
            float ks = 0.f;
#pragma unroll 1
            for (int s = 0; s < 4; ++s) {
                float z = mv_ode();
                float k = fast_tanh(z + bo);
                float wk = (s == 1 || s == 2) ? 2.f : 1.f;
                ks = fmaf(wk, k, ks);
                float n;
                if (s == 3) { h = fmaf(sixth, ks, h); n = h; }
                else        { float a = (s == 2) ? dt : hdt; n = fmaf(a, k, h); }
                pushx(n);
            }
        }
        float zh = mv_wh();
        h = fast_tanh(pv + zh);
        pushx(h);
    }

    // decode: block 0 reads full h (f16) from vbuf[cur]
    if (c == 0 && t < OUT_D) {
        float a = b_dec[t];
#pragma unroll 4
        for (int k = 0; k < HID; ++k) {
            uint16_t hb = vbuf[cur][(k >> 6) * 72 + (k & 63)];
            a = fmaf(W_dec[t * HID + k], (float)__builtin_bit_cast(f16, hb), a);
        }
        out[t] = a;
    }
}

// ---------------------------------------------------------------------------
extern "C" void kernel_launch(void* const* d_in, const int* in_sizes, int n_in,
                              void* d_out, int out_size, void* d_ws, size_t ws_size,
                              hipStream_t stream) {
    const float* tarr  = (const float*)d_in[0];
    const float* x     = (const float*)d_in[1];
    const float* W_in  = (const float*)d_in[2];
    const float* b_in  = (const float*)d_in[3];
    const float* W_h   = (const float*)d_in[4];
    const float* b_h   = (const float*)d_in[5];
    const float* W_ode = (const float*)d_in[6];
    const float* b_ode = (const float*)d_in[7];
    const float* W_dec = (const float*)d_in[8];
    const float* b_dec = (const float*)d_in[9];
    float* out = (float*)d_out;

    uint8_t*  ws       = (uint8_t*)d_ws;
    uint32_t* ode_prep = (uint32_t*)(ws);                       // 512 KB (4x128KB)
    uint32_t* wh_prep  = (uint32_t*)(ws + (512u << 10));        // 512 KB
    uint32_t* vx       = (uint32_t*)(ws + (1u << 20));          // 4 KB tagged exchange
    void*     pre      = (void*)(ws + (1u << 20) + 65536);      // 64 MB f32 or 32 MB f16

    size_t need32 = (1u << 20) + 65536 + (size_t)T_LEN * HID * 4 + 4096;
    int preF32 = (ws_size >= need32) ? 1 : 0;

    hipMemsetAsync(vx, 0, 4096, stream);      // reset tags each launch (replay-safe)
    hipLaunchKernelGGL(k_prep, dim3(8), dim3(NT), 0, stream, W_ode, W_h, ode_prep, wh_prep);
    hipLaunchKernelGGL(k_pre,  dim3(1024), dim3(512), 0, stream, x, W_in, b_in, b_h,
                       (float*)pre, (uint16_t*)pre, preF32);
    hipLaunchKernelGGL(k_scan, dim3(NBLK), dim3(NT), 0, stream, ode_prep, wh_prep,
                       (const float*)pre, (const uint16_t*)pre, preF32,
                       tarr, b_ode, W_dec, b_dec, vx, out);
}

// Round 12
// 541144.727 us; speedup vs baseline: 3.4136x; 1.0985x over previous
//
#include <hip/hip_runtime.h>
#include <stdint.h>

typedef _Float16 f16;
typedef f16 f16x2 __attribute__((ext_vector_type(2)));

#define T_LEN 32768
#define HID   512
#define IN_D  1024
#define OUT_D 128
#define NT    512
#define NWORK 4
#define RPB   128        // rows per worker
#define SLICE_DW 32768   // 128KB W slice per worker, in dwords

__device__ __forceinline__ float dot2f(uint32_t w, uint32_t v, float acc) {
    return __builtin_amdgcn_fdot2(__builtin_bit_cast(f16x2, w),
                                  __builtin_bit_cast(f16x2, v), acc, false);
}
__device__ __forceinline__ float fast_tanh(float z) {
    float e = __expf(2.f * z);
    return 1.f - 2.f * __builtin_amdgcn_rcpf(e + 1.f);
}
// Single-instruction L2 poll load (same-XCD fast path). Self-contained
// waitcnt; "=&v" early-clobber so the dest can never alias the addr pair
// (R11's missing early-clobber on a 2-load asm was the hang).
__device__ __forceinline__ uint32_t ld_sc0(const uint32_t* p) {
    uint32_t d;
    asm volatile("global_load_dword %0, %1, off sc0\n\t"
                 "s_waitcnt vmcnt(0)"
                 : "=&v"(d) : "v"((uint64_t)p) : "memory");
    return d;
}

// ---------------------------------------------------------------------------
// K0: pack W (fp32 -> f16x2) into 4 row-slices. Slice c: rows [c*128,+128).
// dst4[j*NT + t], j in [0,16): rl=j&1, c8=j>>1; element (j,mm):
//   row = c*128 + 2*(t>>3) + rl,  k0 = (t&7)*64 + c8*8 + mm*2.   (= R10)
// ---------------------------------------------------------------------------
__global__ __launch_bounds__(NT) void k_prep(const float* __restrict__ W_ode,
                                             const float* __restrict__ W_h,
                                             uint32_t* __restrict__ ode_prep,
                                             uint32_t* __restrict__ wh_prep) {
    const int bid = blockIdx.x;
    const int c = bid & 3;
    const float* W = (bid >> 2) ? W_h : W_ode;
    uint4* dst = (uint4*)(((bid >> 2) ? wh_prep : ode_prep) + (size_t)c * SLICE_DW);
    const int t = threadIdx.x, rg = t >> 3, kg = t & 7;
    for (int j = 0; j < 16; ++j) {
        const int rl = j & 1, c8 = j >> 1;
        const int row = c * RPB + 2 * rg + rl;
        uint32_t cc[4];
#pragma unroll
        for (int mm = 0; mm < 4; ++mm) {
            const int k0 = kg * 64 + c8 * 8 + mm * 2;
            f16x2 pk;
            pk[0] = (f16)W[row * HID + k0];
            pk[1] = (f16)W[row * HID + k0 + 1];
            cc[mm] = __builtin_bit_cast(uint32_t, pk);
        }
        dst[j * NT + t] = uint4{cc[0], cc[1], cc[2], cc[3]};
    }
}

// ---------------------------------------------------------------------------
// K1: pre[i][j] = W_in @ x_i + b_in + b_h   (fp32 tiled GEMM) — unchanged.
// ---------------------------------------------------------------------------
__global__ __launch_bounds__(512) void k_pre(const float* __restrict__ x,
                                             const float* __restrict__ W_in,
                                             const float* __restrict__ b_in,
                                             const float* __restrict__ b_h,
                                             float* __restrict__ pre32,
                                             uint16_t* __restrict__ pre16,
                                             int preF32) {
    __shared__ float xs[64][34];
    __shared__ float wsh[256][34];
    const int t  = threadIdx.x;
    const int i0 = (blockIdx.x >> 1) * 64;
    const int j0 = (blockIdx.x & 1) * 256;
    const int ti = t >> 5, tj = t & 31;

    float acc[4][8];
#pragma unroll
    for (int a = 0; a < 4; ++a)
#pragma unroll
        for (int b = 0; b < 8; ++b) acc[a][b] = 0.f;

    for (int kb = 0; kb < 32; ++kb) {
        __syncthreads();
        {
            int r = t >> 3, cc = (t & 7) * 4;
            float4 v = *(const float4*)&x[(size_t)(i0 + r) * IN_D + kb * 32 + cc];
            xs[r][cc] = v.x; xs[r][cc + 1] = v.y; xs[r][cc + 2] = v.z; xs[r][cc + 3] = v.w;
        }
        {
            int jr = t >> 1, c0 = (t & 1) * 16;
#pragma unroll
            for (int qd = 0; qd < 4; ++qd) {
                float4 v = *(const float4*)&W_in[(size_t)(j0 + jr) * IN_D + kb * 32 + c0 + qd * 4];
                wsh[jr][c0 + qd * 4]     = v.x; wsh[jr][c0 + qd * 4 + 1] = v.y;
                wsh[jr][c0 + qd * 4 + 2] = v.z; wsh[jr][c0 + qd * 4 + 3] = v.w;
            }
        }
        __syncthreads();
#pragma unroll 4
        for (int k = 0; k < 32; ++k) {
            float xv[4], wv[8];
#pragma unroll
            for (int ii = 0; ii < 4; ++ii) xv[ii] = xs[ti * 4 + ii][k];
#pragma unroll
            for (int jj = 0; jj < 8; ++jj) wv[jj] = wsh[tj + 32 * jj][k];
#pragma unroll
            for (int ii = 0; ii < 4; ++ii)
#pragma unroll
                for (int jj = 0; jj < 8; ++jj)
                    acc[ii][jj] = fmaf(xv[ii], wv[jj], acc[ii][jj]);
        }
    }
#pragma unroll
    for (int ii = 0; ii < 4; ++ii)
#pragma unroll
        for (int jj = 0; jj < 8; ++jj) {
            int ig = i0 + ti * 4 + ii, jg = j0 + tj + 32 * jj;
            float r = acc[ii][jj] + b_in[jg] + b_h[jg];
            if (preF32) pre32[(size_t)ig * HID + jg] = r;
            else        pre16[(size_t)ig * HID + jg] = __builtin_bit_cast(uint16_t, (f16)r);
        }
}

// ---------------------------------------------------------------------------
// K2: sequential scan on 4 workers (grid=25; bid%8==0 work -> same XCD under
// round-robin dispatch). Worker c owns rows [c*128,+128): W_ode in VGPRs,
// W_h in LDS. Exchange = R10's proven tagged-payload protocol; producers
// ALWAYS agent-atomic stores. Consumers: 6 fetch waves x 1 dword/lane; if
// runtime XCC_ID handshake says same-XCD, poll via sc0 L2 loads (~250cy RT)
// with sticky bounded fallback to agent loads (progress guaranteed).
// ---------------------------------------------------------------------------
__global__ __launch_bounds__(NT) void k_scan(
    const uint32_t* __restrict__ ode_prep, const uint32_t* __restrict__ wh_prep,
    const float* __restrict__ pre32, const uint16_t* __restrict__ pre16, int preF32,
    const float* __restrict__ tarr, const float* __restrict__ b_ode,
    const float* __restrict__ W_dec, const float* __restrict__ b_dec,
    uint32_t* vx,
    float* __restrict__ out)
{
    const int bid = blockIdx.x;
    if (bid & 7) return;                              // filler blocks exit
    const int c = bid >> 3;                           // worker id 0..3

    __shared__ uint4 whlds[16 * NT];                  // 128KB: W_h slice
    __shared__ __align__(16) uint16_t vbuf[2][576];   // f16 v, 8 chunks x 144B
    __shared__ int s_fast;

    const int t    = threadIdx.x;
    const int rg   = t >> 3, kg = t & 7;
    const int lane = t & 63;
    const int wv   = t >> 6;                          // wave id 0..7
    const int rloc = 2 * rg + (kg & 1);
    const int row_glob = c * RPB + rloc;
    const uint4* o4 = (const uint4*)(ode_prep + (size_t)c * SLICE_DW);
    const uint4* h4 = (const uint4*)(wh_prep  + (size_t)c * SLICE_DW);

    // ---- one-time XCC placement handshake (agent atomics, co-resident) ----
    if (t == 0) {
        int xcc;
        asm volatile("s_getreg_b32 %0, hwreg(HW_REG_XCC_ID)" : "=s"(xcc));
        __hip_atomic_store(&vx[1024 + c], 0x100u | (uint32_t)(xcc & 0xff),
                           __ATOMIC_RELAXED, __HIP_MEMORY_SCOPE_AGENT);
        uint32_t e[4];
        for (;;) {
            bool ok = true;
#pragma unroll
            for (int b = 0; b < 4; ++b) {
                e[b] = __hip_atomic_load(&vx[1024 + b], __ATOMIC_RELAXED,
                                         __HIP_MEMORY_SCOPE_AGENT);
                ok = ok && ((e[b] & 0x100u) != 0);
            }
            if (ok) break;
        }
        s_fast = (e[0] == e[1] && e[1] == e[2] && e[2] == e[3]) ? 1 : 0;
    }

    uint32_t wreg[64];
#pragma unroll
    for (int j = 0; j < 16; ++j) {
        uint4 w = o4[j * NT + t];
        wreg[4 * j] = w.x; wreg[4 * j + 1] = w.y;
        wreg[4 * j + 2] = w.z; wreg[4 * j + 3] = w.w;
    }
#pragma unroll
    for (int j = 0; j < 16; ++j)
        whlds[j * NT + t] = h4[j * NT + t];

    const float bo = b_ode[row_glob];
    __syncthreads();
    int fastp = s_fast;                 // per-thread sticky fast-poll flag

    int cur = 1;
    uint32_t m = 0;

    auto reduceZ = [&](float a0, float a1) -> float {
        float mine = (kg & 1) ? a1 : a0;
        float oth  = (kg & 1) ? a0 : a1;
        float b = mine + __shfl_xor(oth, 1);
        b += __shfl_xor(b, 2);
        b += __shfl_xor(b, 4);
        return b;                                // z for row rloc, all lanes
    };

    auto mv_ode = [&]() -> float {
        float a0 = 0.f, a1 = 0.f;
        const char* vb = (const char*)&vbuf[cur][0] + kg * 144;
#pragma unroll
        for (int c8 = 0; c8 < 8; ++c8) {
            const uint4 vv = *(const uint4*)(vb + c8 * 16);
            const int j0 = (c8 * 2) * 4, j1 = (c8 * 2 + 1) * 4;
            a0 = dot2f(wreg[j0],     vv.x, a0);
            a0 = dot2f(wreg[j0 + 1], vv.y, a0);
            a0 = dot2f(wreg[j0 + 2], vv.z, a0);
            a0 = dot2f(wreg[j0 + 3], vv.w, a0);
            a1 = dot2f(wreg[j1],     vv.x, a1);
            a1 = dot2f(wreg[j1 + 1], vv.y, a1);
            a1 = dot2f(wreg[j1 + 2], vv.z, a1);
            a1 = dot2f(wreg[j1 + 3], vv.w, a1);
        }
        return reduceZ(a0, a1);
    };

    auto mv_wh = [&]() -> float {
        float a0 = 0.f, a1 = 0.f;
        const char* vb = (const char*)&vbuf[cur][0] + kg * 144;
#pragma unroll
        for (int c8 = 0; c8 < 8; ++c8) {
            const uint4 vv = *(const uint4*)(vb + c8 * 16);
            const uint4 w0 = whlds[(c8 * 2) * NT + t];
            const uint4 w1 = whlds[(c8 * 2 + 1) * NT + t];
            a0 = dot2f(w0.x, vv.x, a0); a0 = dot2f(w0.y, vv.y, a0);
            a0 = dot2f(w0.z, vv.z, a0); a0 = dot2f(w0.w, vv.w, a0);
            a1 = dot2f(w1.x, vv.x, a1); a1 = dot2f(w1.y, vv.y, a1);
            a1 = dot2f(w1.z, vv.z, a1); a1 = dot2f(w1.w, vv.w, a1);
        }
        return reduceZ(a0, a1);
    };

    // publish own v-slice (tagged dwords) + fetch 3 remote slices; 1 barrier.
    auto pushx = [&](float n) {
        ++m;
        const uint32_t mt = m & 0xffffu;
        const int nxt = cur ^ 1;
        uint32_t* slot = vx + (m & 1) * 512;
        const uint16_t nb = __builtin_bit_cast(uint16_t, (f16)n);
        if (kg < 2) {                                   // owner lanes publish
            vbuf[nxt][(row_glob >> 6) * 72 + (row_glob & 63)] = nb;
            __hip_atomic_store(&slot[c * RPB + rloc], (mt << 16) | (uint32_t)nb,
                               __ATOMIC_RELAXED, __HIP_MEMORY_SCOPE_AGENT);
        }
        if (wv >= 1 && wv <= 6) {                       // 6 fetch waves
            const int task = wv - 1;                    // 0..5
            const int fb   = (c + 1 + (task >> 1)) & 3; // remote worker
            const int half = task & 1;                  // 64-row half
            const uint32_t* p0 = &slot[fb * RPB + half * 64 + lane];
            uint32_t d0;
            int tries = 0;
            for (;;) {
                d0 = fastp ? ld_sc0(p0)
                           : __hip_atomic_load(p0, __ATOMIC_RELAXED,
                                               __HIP_MEMORY_SCOPE_AGENT);
                if (__all((d0 >> 16) == mt)) break;
                if (fastp && ++tries > 2048) fastp = 0; // sticky safe fallback
            }
            vbuf[nxt][(2 * fb + half) * 72 + lane] = (uint16_t)d0;
        }
        __syncthreads();
        cur = nxt;
    };

    // h0 = tanh(pre[0][row]); exchange as m=1
    float h;
    {
        float p0 = preF32 ? pre32[row_glob] : (float)__builtin_bit_cast(f16, pre16[row_glob]);
        h = fast_tanh(p0);
    }
    pushx(h);
    float tprev = tarr[0];

#pragma unroll 1
    for (int i = 1; i < T_LEN; ++i) {
        float tc  = tarr[i];
        float dtt = tc - tprev; tprev = tc;
        float dt  = 0.25f * dtt;            // N_SUB = 4
        float hdt = 0.5f * dt;
        float sixth = dt * (1.f / 6.f);
        float pv = preF32 ? pre32[(size_t)i * HID + row_glob]
                          : (float)__builtin_bit_cast(f16, pre16[(size_t)i * HID + row_glob]);
#pragma unroll 1
        for (int sub = 0; sub < 4; ++sub) {
            float ks = 0.f;
#pragma unroll 1
            for (int s = 0; s < 4; ++s) {
                float z = mv_ode();
                float k = fast_tanh(z + bo);
                float wk = (s == 1 || s == 2) ? 2.f : 1.f;
                ks = fmaf(wk, k, ks);
                float n;
                if (s == 3) { h = fmaf(sixth, ks, h); n = h; }
                else        { float a = (s == 2) ? dt : hdt; n = fmaf(a, k, h); }
                pushx(n);
            }
        }
        float zh = mv_wh();
        h = fast_tanh(pv + zh);
        pushx(h);
    }

    // decode: worker 0 reads full h (f16) from vbuf[cur]
    if (c == 0 && t < OUT_D) {
        float a = b_dec[t];
#pragma unroll 4
        for (int k = 0; k < HID; ++k) {
            uint16_t hb = vbuf[cur][(k >> 6) * 72 + (k & 63)];
            a = fmaf(W_dec[t * HID + k], (float)__builtin_bit_cast(f16, hb), a);
        }
        out[t] = a;
    }
}

// ---------------------------------------------------------------------------
extern "C" void kernel_launch(void* const* d_in, const int* in_sizes, int n_in,
                              void* d_out, int out_size, void* d_ws, size_t ws_size,
                              hipStream_t stream) {
    const float* tarr  = (const float*)d_in[0];
    const float* x     = (const float*)d_in[1];
    const float* W_in  = (const float*)d_in[2];
    const float* b_in  = (const float*)d_in[3];
    const float* W_h   = (const float*)d_in[4];
    const float* b_h   = (const float*)d_in[5];
    const float* W_ode = (const float*)d_in[6];
    const float* b_ode = (const float*)d_in[7];
    const float* W_dec = (const float*)d_in[8];
    const float* b_dec = (const float*)d_in[9];
    float* out = (float*)d_out;

    uint8_t*  ws       = (uint8_t*)d_ws;
    uint32_t* ode_prep = (uint32_t*)(ws);                       // 512 KB (4x128KB)
    uint32_t* wh_prep  = (uint32_t*)(ws + (512u << 10));        // 512 KB
    uint32_t* vx       = (uint32_t*)(ws + (1u << 20));          // exchange + xcc
    void*     pre      = (void*)(ws + (1u << 20) + 65536);      // 64 MB f32 or 32 MB f16

    size_t need32 = (1u << 20) + 65536 + (size_t)T_LEN * HID * 4 + 4096;
    int preF32 = (ws_size >= need32) ? 1 : 0;

    hipMemsetAsync(vx, 0, 8192, stream);      // reset tags + xcc slots (replay-safe)
    hipLaunchKernelGGL(k_prep, dim3(8), dim3(NT), 0, stream, W_ode, W_h, ode_prep, wh_prep);
    hipLaunchKernelGGL(k_pre,  dim3(1024), dim3(512), 0, stream, x, W_in, b_in, b_h,
                       (float*)pre, (uint16_t*)pre, preF32);
    hipLaunchKernelGGL(k_scan, dim3(25), dim3(NT), 0, stream, ode_prep, wh_prep,
                       (const float*)pre, (const uint16_t*)pre, preF32,
                       tarr, b_ode, W_dec, b_dec, vx, out);
}